// Round 8
// baseline (338.134 us; speedup 1.0000x reference)
//
#include <hip/hip_runtime.h>
#include <hip/hip_fp16.h>

#define N_NODES 50000
#define N_EDGES 800000
#define NEG_SLOPE 0.2f
#define LN_EPS 1e-5f
#define NB_SCAN 196      // ceil(N_NODES/256)
#define ALPHA_BLOCKS 1024
#define DEG_BLOCKS 3125  // ceil(N_EDGES/256)

// ---------------- k_pre: tiny precomputes ----------------
// M[hd] = W_node[:,hd-block] @ W_scale[hd-block,:]  (4 x 64 x 64)
// qu[hd][k] = sum_j Wn[k, hd*64+j]*a_u[hd][j] ; qv likewise ; cu/cv = b-dot terms
// cvec[c] = bias[c] + sum_kk bn[kk]*Ws[kk][c]
__global__ __launch_bounds__(256) void k_pre(
    const float* __restrict__ Wn, const float* __restrict__ bn,
    const float* __restrict__ att, const float* __restrict__ Ws,
    const float* __restrict__ bias,
    float* __restrict__ qu, float* __restrict__ qv, float* __restrict__ cuv,
    float* __restrict__ M, float* __restrict__ cvec)
{
    const int b = blockIdx.x, t = threadIdx.x;
    if (b < 64) {
        int e = b * 256 + t;                 // [0, 16384)
        int hd = e >> 12, k = (e >> 6) & 63, c = e & 63;
        float s = 0.f;
        for (int j = 0; j < 64; ++j)
            s = fmaf(Wn[k * 256 + hd * 64 + j], Ws[(hd * 64 + j) * 64 + c], s);
        M[e] = s;
    } else if (b == 64) {
        int hd = t >> 6, k = t & 63;
        float su = 0.f, sv = 0.f;
        for (int j = 0; j < 64; ++j) {
            float w = Wn[k * 256 + hd * 64 + j];
            su = fmaf(w, att[hd * 128 + j], su);
            sv = fmaf(w, att[hd * 128 + 64 + j], sv);
        }
        qu[hd * 64 + k] = su;
        qv[hd * 64 + k] = sv;
        if (t < 8) {
            int hh = t & 3;
            const float* a = att + hh * 128 + (t >> 2) * 64;
            float s = 0.f;
            for (int j = 0; j < 64; ++j) s = fmaf(bn[hh * 64 + j], a[j], s);
            cuv[t] = s;                      // [0..3]=cu, [4..7]=cv
        }
    } else {
        if (t < 64) {
            float s = bias[t];
            for (int kk = 0; kk < 256; ++kk) s = fmaf(bn[kk], Ws[kk * 64 + t], s);
            cvec[t] = s;
        }
    }
}

// ---------------- k_front2: [0,ALPHA_BLOCKS) alphas + h16 cast; rest: degree+rank ----------------
// alpha part: one wave per node. lane l owns dim l. 8 butterfly-reduced dots.
__global__ __launch_bounds__(256) void k_front2(
    const float* __restrict__ h, const int* __restrict__ dst,
    const float* __restrict__ qu, const float* __restrict__ qv, const float* __restrict__ cuv,
    __half* __restrict__ h16, float* __restrict__ alpha_u, float* __restrict__ alpha_v,
    int* __restrict__ deg, int* __restrict__ rank)
{
    const int t = threadIdx.x;
    if (blockIdx.x >= ALPHA_BLOCKS) {
        int e = (blockIdx.x - ALPHA_BLOCKS) * 256 + t;
        if (e < N_EDGES) rank[e] = atomicAdd(&deg[dst[e]], 1);
        return;
    }
    const int lane = t & 63;
    const int wid = blockIdx.x * 4 + (t >> 6);
    const float qur0 = qu[lane], qur1 = qu[64 + lane], qur2 = qu[128 + lane], qur3 = qu[192 + lane];
    const float qvr0 = qv[lane], qvr1 = qv[64 + lane], qvr2 = qv[128 + lane], qvr3 = qv[192 + lane];
    const float4 cu = *(const float4*)cuv;
    const float4 cv = *(const float4*)(cuv + 4);
    for (int n = wid; n < N_NODES; n += ALPHA_BLOCKS * 4) {
        float hv = h[(size_t)n * 64 + lane];
        h16[(size_t)n * 64 + lane] = __float2half(hv);
        float pu0 = hv * qur0, pu1 = hv * qur1, pu2 = hv * qur2, pu3 = hv * qur3;
        float pv0 = hv * qvr0, pv1 = hv * qvr1, pv2 = hv * qvr2, pv3 = hv * qvr3;
#pragma unroll
        for (int off = 32; off; off >>= 1) {
            pu0 += __shfl_xor(pu0, off);
            pu1 += __shfl_xor(pu1, off);
            pu2 += __shfl_xor(pu2, off);
            pu3 += __shfl_xor(pu3, off);
            pv0 += __shfl_xor(pv0, off);
            pv1 += __shfl_xor(pv1, off);
            pv2 += __shfl_xor(pv2, off);
            pv3 += __shfl_xor(pv3, off);
        }
        if (lane == 0) {
            *(float4*)(alpha_u + n * 4) = make_float4(pu0 + cu.x, pu1 + cu.y, pu2 + cu.z, pu3 + cu.w);
            *(float4*)(alpha_v + n * 4) = make_float4(pv0 + cv.x, pv1 + cv.y, pv2 + cv.z, pv3 + cv.w);
        }
    }
}

// ---------------- scan (3 small stages) ----------------
__device__ __forceinline__ int wave_incl_scan(int x, int lane) {
#pragma unroll
    for (int off = 1; off < 64; off <<= 1) {
        int y = __shfl_up(x, off);
        if (lane >= off) x += y;
    }
    return x;
}

__global__ __launch_bounds__(256) void k_scan1(const int* __restrict__ deg,
                                               int* __restrict__ rowptr, int* __restrict__ bsum) {
    __shared__ int wsum[4];
    const int t = threadIdx.x, lane = t & 63, w = t >> 6;
    const int i = blockIdx.x * 256 + t;
    int x = (i < N_NODES) ? deg[i] : 0;
    int incl = wave_incl_scan(x, lane);
    if (lane == 63) wsum[w] = incl;
    __syncthreads();
    int pre = 0;
    for (int ww = 0; ww < w; ++ww) pre += wsum[ww];
    if (i < N_NODES) rowptr[i] = pre + incl - x;
    if (t == 255) bsum[blockIdx.x] = pre + incl;
}

__global__ __launch_bounds__(256) void k_scan2(const int* __restrict__ bsum, int* __restrict__ boff) {
    __shared__ int wsum[4];
    const int t = threadIdx.x, lane = t & 63, w = t >> 6;
    int x = (t < NB_SCAN) ? bsum[t] : 0;
    int incl = wave_incl_scan(x, lane);
    if (lane == 63) wsum[w] = incl;
    __syncthreads();
    int pre = 0;
    for (int ww = 0; ww < w; ++ww) pre += wsum[ww];
    if (t < NB_SCAN) boff[t] = pre + incl - x;
}

__global__ __launch_bounds__(256) void k_scan3(int* __restrict__ rowptr, const int* __restrict__ boff) {
    const int i = blockIdx.x * 256 + threadIdx.x;
    if (i < N_NODES) rowptr[i] += boff[blockIdx.x];
    if (i == 0) rowptr[N_NODES] = N_EDGES;
}

// ---------------- scatter: atomic-free via precomputed rank ----------------
__global__ __launch_bounds__(256) void k_scatter(const int* __restrict__ src, const int* __restrict__ dst,
                                                 const int* __restrict__ rowptr, const int* __restrict__ rank,
                                                 int* __restrict__ csr_src) {
    int e = blockIdx.x * 256 + threadIdx.x;
    if (e < N_EDGES) csr_src[rowptr[dst[e]] + rank[e]] = src[e];
}

// ---------------- k_agg2: one wave per node; gather h16[src] (2B/lane); 4 head-accs per lane ----
// exp without max subtraction (softmax shift-invariant; logits ~ +-6, fp32-safe).
// aggh[n][hd][k]: lane=k holds acc for all 4 heads. Normalized before store.
__global__ __launch_bounds__(256) void k_agg2(
    const int* __restrict__ rowptr, const int* __restrict__ csr_src,
    const float* __restrict__ alpha_u, const float* __restrict__ alpha_v,
    const __half* __restrict__ h16, float* __restrict__ aggh, int n0, int n1)
{
    const int lane = threadIdx.x & 63;
    const int wid = __builtin_amdgcn_readfirstlane((int)((blockIdx.x * 256 + threadIdx.x) >> 6));
    const int nwaves = (gridDim.x * 256) >> 6;
    for (int n = n0 + wid; n < n1; n += nwaves) {
        const int r0 = rowptr[n], r1 = rowptr[n + 1];
        const float4 av = *(const float4*)(alpha_v + (size_t)n * 4);
        float d0 = 0.f, d1 = 0.f, d2 = 0.f, d3 = 0.f;
        float a0 = 0.f, a1 = 0.f, a2 = 0.f, a3 = 0.f;
        const int rlast = r1 - 1;
        for (int j = r0; j < r1; j += 8) {
            int s[8];
#pragma unroll
            for (int i = 0; i < 8; ++i) {
                int jj = j + i;
                s[i] = __builtin_amdgcn_readfirstlane(csr_src[jj < rlast ? jj : rlast]);
            }
            float hv[8];
#pragma unroll
            for (int i = 0; i < 8; ++i)
                hv[i] = __half2float(h16[(size_t)s[i] * 64 + lane]);
            float4 au[8];
#pragma unroll
            for (int i = 0; i < 8; ++i)
                au[i] = *(const float4*)(alpha_u + (size_t)s[i] * 4);
#pragma unroll
            for (int i = 0; i < 8; ++i) {
                const bool valid = (j + i < r1);
                float l0 = au[i].x + av.x; l0 = l0 > 0.f ? l0 : NEG_SLOPE * l0;
                float l1 = au[i].y + av.y; l1 = l1 > 0.f ? l1 : NEG_SLOPE * l1;
                float l2 = au[i].z + av.z; l2 = l2 > 0.f ? l2 : NEG_SLOPE * l2;
                float l3 = au[i].w + av.w; l3 = l3 > 0.f ? l3 : NEG_SLOPE * l3;
                float e0 = valid ? __expf(l0) : 0.f;
                float e1 = valid ? __expf(l1) : 0.f;
                float e2 = valid ? __expf(l2) : 0.f;
                float e3 = valid ? __expf(l3) : 0.f;
                d0 += e0; a0 = fmaf(e0, hv[i], a0);
                d1 += e1; a1 = fmaf(e1, hv[i], a1);
                d2 += e2; a2 = fmaf(e2, hv[i], a2);
                d3 += e3; a3 = fmaf(e3, hv[i], a3);
            }
        }
        const float i0 = 1.0f / fmaxf(d0, 1e-16f);
        const float i1 = 1.0f / fmaxf(d1, 1e-16f);
        const float i2 = 1.0f / fmaxf(d2, 1e-16f);
        const float i3 = 1.0f / fmaxf(d3, 1e-16f);
        float* __restrict__ arow = aggh + (size_t)n * 256;
        arow[lane]       = a0 * i0;
        arow[64 + lane]  = a1 * i1;
        arow[128 + lane] = a2 * i2;
        arow[192 + lane] = a3 * i3;
    }
}

// ---------------- k_post: h_new = sum_hd aggh[n,hd,:] @ M_hd + cvec; +h; LN; relu ----------------
// wave w handles head w's 64x64 block of M; wreg pinned to VGPRs via opaque asm.
__global__ __launch_bounds__(256, 3) void k_post(
    const float* __restrict__ aggh, const float* __restrict__ M,
    const float* __restrict__ cvec, const float* __restrict__ h,
    const float* __restrict__ gamma_, const float* __restrict__ beta_,
    float* __restrict__ out)
{
    __shared__ float aggs[8][256];
    __shared__ float part[8][4][64];
    const int t = threadIdx.x;
    const int w = t >> 6;   // wave id == head id (k-slice)
    const int c = t & 63;
    float wreg[64];
#pragma unroll
    for (int k = 0; k < 64; ++k) {
        wreg[k] = M[(size_t)(w * 64 + k) * 64 + c];
        asm volatile("" : "+v"(wreg[k]));   // pin: forbid rematerialization from L2
    }
    const float cvc = cvec[c], gc = gamma_[c], btc = beta_[c];

    // N_NODES % 8 == 0 -> no tail guards
    for (int nb = blockIdx.x * 8; nb < N_NODES; nb += gridDim.x * 8) {
#pragma unroll
        for (int i = 0; i < 2; ++i) {
            int f = i * 256 + t;                 // float4 index in [0,512)
            int node = f >> 6, col4 = f & 63;
            float4 v = *(const float4*)(aggh + (size_t)(nb + node) * 256 + col4 * 4);
            *(float4*)&aggs[node][col4 * 4] = v;
        }
        __syncthreads();
#pragma unroll
        for (int n = 0; n < 8; ++n) {
            float p = 0.f;
#pragma unroll
            for (int k4 = 0; k4 < 16; ++k4) {
                float4 avv = *(const float4*)&aggs[n][w * 64 + k4 * 4];  // broadcast read
                p = fmaf(avv.x, wreg[k4 * 4 + 0], p);
                p = fmaf(avv.y, wreg[k4 * 4 + 1], p);
                p = fmaf(avv.z, wreg[k4 * 4 + 2], p);
                p = fmaf(avv.w, wreg[k4 * 4 + 3], p);
            }
            part[n][w][c] = p;
        }
        __syncthreads();
#pragma unroll
        for (int i = 0; i < 2; ++i) {
            const int n = w + i * 4;        // wave w finishes nodes nb+w, nb+w+4
            const int gn = nb + n;
            float x = part[n][0][c] + part[n][1][c] + part[n][2][c] + part[n][3][c]
                      + cvc + h[(size_t)gn * 64 + c];
            float mu = x;
#pragma unroll
            for (int off = 32; off; off >>= 1) mu += __shfl_xor(mu, off);
            mu *= (1.0f / 64.0f);
            const float xm = x - mu;
            float v2 = xm * xm;
#pragma unroll
            for (int off = 32; off; off >>= 1) v2 += __shfl_xor(v2, off);
            v2 *= (1.0f / 64.0f);
            const float xn = xm * rsqrtf(v2 + LN_EPS);
            out[(size_t)gn * 64 + c] = fmaxf(xn * gc + btc, 0.0f);
        }
        __syncthreads();
    }
}

extern "C" void kernel_launch(void* const* d_in, const int* in_sizes, int n_in,
                              void* d_out, int out_size, void* d_ws, size_t ws_size,
                              hipStream_t stream) {
    const float* h      = (const float*)d_in[0];
    const int*   src    = (const int*)d_in[1];
    const int*   dst    = (const int*)d_in[2];
    const float* Wn     = (const float*)d_in[3];
    const float* bn     = (const float*)d_in[4];
    const float* att    = (const float*)d_in[5];
    const float* Ws     = (const float*)d_in[6];
    const float* bias   = (const float*)d_in[7];
    const float* gamma_ = (const float*)d_in[8];
    const float* beta_  = (const float*)d_in[9];
    float* out = (float*)d_out;

    char* ws = (char*)d_ws;
    size_t off = 0;
    auto alloc = [&](size_t bytes) { void* p = ws + off; off = (off + bytes + 255) & ~(size_t)255; return p; };
    __half* h16    = (__half*)alloc((size_t)N_NODES * 64 * 2);   // 6.4 MB
    float* aggh    = (float*)alloc((size_t)N_NODES * 256 * 4);   // 51.2 MB
    float* alpha_u = (float*)alloc((size_t)N_NODES * 4 * 4);
    float* alpha_v = (float*)alloc((size_t)N_NODES * 4 * 4);
    int*   deg     = (int*)alloc((size_t)N_NODES * 4);
    int*   rowptr  = (int*)alloc((size_t)(N_NODES + 1) * 4);
    int*   rank    = (int*)alloc((size_t)N_EDGES * 4);           // 3.2 MB
    int*   bsum    = (int*)alloc((size_t)NB_SCAN * 4);
    int*   boff    = (int*)alloc((size_t)NB_SCAN * 4);
    int*   csr_src = (int*)alloc((size_t)N_EDGES * 4);           // 3.2 MB
    float* qu      = (float*)alloc(256 * 4);
    float* qv      = (float*)alloc(256 * 4);
    float* cuv     = (float*)alloc(8 * 4);
    float* Mbuf    = (float*)alloc(16384 * 4);                   // 64 KB
    float* cvec    = (float*)alloc(64 * 4);

    hipMemsetAsync(deg, 0, (size_t)N_NODES * 4, stream);

    k_pre<<<66, 256, 0, stream>>>(Wn, bn, att, Ws, bias, qu, qv, cuv, Mbuf, cvec);
    k_front2<<<ALPHA_BLOCKS + DEG_BLOCKS, 256, 0, stream>>>(h, dst, qu, qv, cuv,
                                                            h16, alpha_u, alpha_v, deg, rank);
    k_scan1<<<NB_SCAN, 256, 0, stream>>>(deg, rowptr, bsum);
    k_scan2<<<1, 256, 0, stream>>>(bsum, boff);
    k_scan3<<<NB_SCAN, 256, 0, stream>>>(rowptr, boff);
    k_scatter<<<DEG_BLOCKS, 256, 0, stream>>>(src, dst, rowptr, rank, csr_src);
    k_agg2<<<2048, 256, 0, stream>>>(rowptr, csr_src, alpha_u, alpha_v, h16, aggh, 0, N_NODES / 2);
    k_agg2<<<2048, 256, 0, stream>>>(rowptr, csr_src, alpha_u, alpha_v, h16, aggh, N_NODES / 2, N_NODES);
    k_post<<<2048, 256, 0, stream>>>(aggh, Mbuf, cvec, h, gamma_, beta_, out);
}

// Round 10
// 279.944 us; speedup vs baseline: 1.2079x; 1.2079x over previous
//
#include <hip/hip_runtime.h>
#include <hip/hip_fp16.h>

#define N_NODES 50000
#define N_EDGES 800000
#define NEG_SLOPE 0.2f
#define LN_EPS 1e-5f
#define NB_SCAN 196      // ceil(N_NODES/256)
#define ALPHA_BLOCKS 1024
#define DEG_BLOCKS 3125  // ceil(N_EDGES/256)

typedef _Float16 f16;
typedef f16 f16x4 __attribute__((ext_vector_type(4)));
typedef f16 f16x8 __attribute__((ext_vector_type(8)));
typedef float f32x4 __attribute__((ext_vector_type(4)));

// ---------------- k_pre: tiny precomputes ----------------
// Mt16[c][hd*64+k] = (f16) sum_j Wn[k][hd*64+j] * Ws[hd*64+j][c]   (transposed, fp16)
// qu[hd][k], qv[hd][k]: alpha projection vectors; cuv: bias dots; cvec = bias + bn@Ws
__global__ __launch_bounds__(256) void k_pre(
    const float* __restrict__ Wn, const float* __restrict__ bn,
    const float* __restrict__ att, const float* __restrict__ Ws,
    const float* __restrict__ bias,
    float* __restrict__ qu, float* __restrict__ qv, float* __restrict__ cuv,
    f16* __restrict__ Mt16, float* __restrict__ cvec)
{
    const int b = blockIdx.x, t = threadIdx.x;
    if (b < 64) {
        int e = b * 256 + t;                 // [0, 16384)
        int hd = e >> 12, k = (e >> 6) & 63, c = e & 63;
        float s = 0.f;
        for (int j = 0; j < 64; ++j)
            s = fmaf(Wn[k * 256 + hd * 64 + j], Ws[(hd * 64 + j) * 64 + c], s);
        Mt16[c * 256 + hd * 64 + k] = (f16)s;
    } else if (b == 64) {
        int hd = t >> 6, k = t & 63;
        float su = 0.f, sv = 0.f;
        for (int j = 0; j < 64; ++j) {
            float w = Wn[k * 256 + hd * 64 + j];
            su = fmaf(w, att[hd * 128 + j], su);
            sv = fmaf(w, att[hd * 128 + 64 + j], sv);
        }
        qu[hd * 64 + k] = su;
        qv[hd * 64 + k] = sv;
        if (t < 8) {
            int hh = t & 3;
            const float* a = att + hh * 128 + (t >> 2) * 64;
            float s = 0.f;
            for (int j = 0; j < 64; ++j) s = fmaf(bn[hh * 64 + j], a[j], s);
            cuv[t] = s;                      // [0..3]=cu, [4..7]=cv
        }
    } else {
        if (t < 64) {
            float s = bias[t];
            for (int kk = 0; kk < 256; ++kk) s = fmaf(bn[kk], Ws[kk * 64 + t], s);
            cvec[t] = s;
        }
    }
}

// ---------------- k_front2: [0,ALPHA_BLOCKS) alphas + h16 cast; rest: degree+rank ----------------
__global__ __launch_bounds__(256) void k_front2(
    const float* __restrict__ h, const int* __restrict__ dst,
    const float* __restrict__ qu, const float* __restrict__ qv, const float* __restrict__ cuv,
    __half* __restrict__ h16, float* __restrict__ alpha_u, float* __restrict__ alpha_v,
    int* __restrict__ deg, int* __restrict__ rank)
{
    const int t = threadIdx.x;
    if (blockIdx.x >= ALPHA_BLOCKS) {
        int e = (blockIdx.x - ALPHA_BLOCKS) * 256 + t;
        if (e < N_EDGES) rank[e] = atomicAdd(&deg[dst[e]], 1);
        return;
    }
    const int lane = t & 63;
    const int wid = blockIdx.x * 4 + (t >> 6);
    const float qur0 = qu[lane], qur1 = qu[64 + lane], qur2 = qu[128 + lane], qur3 = qu[192 + lane];
    const float qvr0 = qv[lane], qvr1 = qv[64 + lane], qvr2 = qv[128 + lane], qvr3 = qv[192 + lane];
    const float4 cu = *(const float4*)cuv;
    const float4 cv = *(const float4*)(cuv + 4);
    for (int n = wid; n < N_NODES; n += ALPHA_BLOCKS * 4) {
        float hv = h[(size_t)n * 64 + lane];
        h16[(size_t)n * 64 + lane] = __float2half(hv);
        float pu0 = hv * qur0, pu1 = hv * qur1, pu2 = hv * qur2, pu3 = hv * qur3;
        float pv0 = hv * qvr0, pv1 = hv * qvr1, pv2 = hv * qvr2, pv3 = hv * qvr3;
#pragma unroll
        for (int off = 32; off; off >>= 1) {
            pu0 += __shfl_xor(pu0, off);
            pu1 += __shfl_xor(pu1, off);
            pu2 += __shfl_xor(pu2, off);
            pu3 += __shfl_xor(pu3, off);
            pv0 += __shfl_xor(pv0, off);
            pv1 += __shfl_xor(pv1, off);
            pv2 += __shfl_xor(pv2, off);
            pv3 += __shfl_xor(pv3, off);
        }
        if (lane == 0) {
            *(float4*)(alpha_u + n * 4) = make_float4(pu0 + cu.x, pu1 + cu.y, pu2 + cu.z, pu3 + cu.w);
            *(float4*)(alpha_v + n * 4) = make_float4(pv0 + cv.x, pv1 + cv.y, pv2 + cv.z, pv3 + cv.w);
        }
    }
}

// ---------------- scan (3 small stages) ----------------
__device__ __forceinline__ int wave_incl_scan(int x, int lane) {
#pragma unroll
    for (int off = 1; off < 64; off <<= 1) {
        int y = __shfl_up(x, off);
        if (lane >= off) x += y;
    }
    return x;
}

__global__ __launch_bounds__(256) void k_scan1(const int* __restrict__ deg,
                                               int* __restrict__ rowptr, int* __restrict__ bsum) {
    __shared__ int wsum[4];
    const int t = threadIdx.x, lane = t & 63, w = t >> 6;
    const int i = blockIdx.x * 256 + t;
    int x = (i < N_NODES) ? deg[i] : 0;
    int incl = wave_incl_scan(x, lane);
    if (lane == 63) wsum[w] = incl;
    __syncthreads();
    int pre = 0;
    for (int ww = 0; ww < w; ++ww) pre += wsum[ww];
    if (i < N_NODES) rowptr[i] = pre + incl - x;
    if (t == 255) bsum[blockIdx.x] = pre + incl;
}

__global__ __launch_bounds__(256) void k_scan2(const int* __restrict__ bsum, int* __restrict__ boff) {
    __shared__ int wsum[4];
    const int t = threadIdx.x, lane = t & 63, w = t >> 6;
    int x = (t < NB_SCAN) ? bsum[t] : 0;
    int incl = wave_incl_scan(x, lane);
    if (lane == 63) wsum[w] = incl;
    __syncthreads();
    int pre = 0;
    for (int ww = 0; ww < w; ++ww) pre += wsum[ww];
    if (t < NB_SCAN) boff[t] = pre + incl - x;
}

__global__ __launch_bounds__(256) void k_scan3(int* __restrict__ rowptr, const int* __restrict__ boff) {
    const int i = blockIdx.x * 256 + threadIdx.x;
    if (i < N_NODES) rowptr[i] += boff[blockIdx.x];
    if (i == 0) rowptr[N_NODES] = N_EDGES;
}

// ---------------- scatter: atomic-free via precomputed rank ----------------
__global__ __launch_bounds__(256) void k_scatter(const int* __restrict__ src, const int* __restrict__ dst,
                                                 const int* __restrict__ rowptr, const int* __restrict__ rank,
                                                 int* __restrict__ csr_src) {
    int e = blockIdx.x * 256 + threadIdx.x;
    if (e < N_EDGES) csr_src[rowptr[dst[e]] + rank[e]] = src[e];
}

// ---------------- k_agg2: one wave per node; gather h16[src]; 4 head-accs per lane; fp16 out ----
__global__ __launch_bounds__(256) void k_agg2(
    const int* __restrict__ rowptr, const int* __restrict__ csr_src,
    const float* __restrict__ alpha_u, const float* __restrict__ alpha_v,
    const __half* __restrict__ h16, f16* __restrict__ aggh16, int n0, int n1)
{
    const int lane = threadIdx.x & 63;
    const int wid = __builtin_amdgcn_readfirstlane((int)((blockIdx.x * 256 + threadIdx.x) >> 6));
    const int nwaves = (gridDim.x * 256) >> 6;
    for (int n = n0 + wid; n < n1; n += nwaves) {
        const int r0 = rowptr[n], r1 = rowptr[n + 1];
        const float4 av = *(const float4*)(alpha_v + (size_t)n * 4);
        float d0 = 0.f, d1 = 0.f, d2 = 0.f, d3 = 0.f;
        float a0 = 0.f, a1 = 0.f, a2 = 0.f, a3 = 0.f;
        const int rlast = r1 - 1;
        for (int j = r0; j < r1; j += 8) {
            int s[8];
#pragma unroll
            for (int i = 0; i < 8; ++i) {
                int jj = j + i;
                s[i] = __builtin_amdgcn_readfirstlane(csr_src[jj < rlast ? jj : rlast]);
            }
            float hv[8];
#pragma unroll
            for (int i = 0; i < 8; ++i)
                hv[i] = __half2float(h16[(size_t)s[i] * 64 + lane]);
            float4 au[8];
#pragma unroll
            for (int i = 0; i < 8; ++i)
                au[i] = *(const float4*)(alpha_u + (size_t)s[i] * 4);
#pragma unroll
            for (int i = 0; i < 8; ++i) {
                const bool valid = (j + i < r1);
                float l0 = au[i].x + av.x; l0 = l0 > 0.f ? l0 : NEG_SLOPE * l0;
                float l1 = au[i].y + av.y; l1 = l1 > 0.f ? l1 : NEG_SLOPE * l1;
                float l2 = au[i].z + av.z; l2 = l2 > 0.f ? l2 : NEG_SLOPE * l2;
                float l3 = au[i].w + av.w; l3 = l3 > 0.f ? l3 : NEG_SLOPE * l3;
                float e0 = valid ? __expf(l0) : 0.f;
                float e1 = valid ? __expf(l1) : 0.f;
                float e2 = valid ? __expf(l2) : 0.f;
                float e3 = valid ? __expf(l3) : 0.f;
                d0 += e0; a0 = fmaf(e0, hv[i], a0);
                d1 += e1; a1 = fmaf(e1, hv[i], a1);
                d2 += e2; a2 = fmaf(e2, hv[i], a2);
                d3 += e3; a3 = fmaf(e3, hv[i], a3);
            }
        }
        const float i0 = 1.0f / fmaxf(d0, 1e-16f);
        const float i1 = 1.0f / fmaxf(d1, 1e-16f);
        const float i2 = 1.0f / fmaxf(d2, 1e-16f);
        const float i3 = 1.0f / fmaxf(d3, 1e-16f);
        f16* __restrict__ arow = aggh16 + (size_t)n * 256;
        arow[lane]       = (f16)(a0 * i0);
        arow[64 + lane]  = (f16)(a1 * i1);
        arow[128 + lane] = (f16)(a2 * i2);
        arow[192 + lane] = (f16)(a3 * i3);
    }
}

// ---------------- k_post_mfma: h_new = aggh16 @ Mt16^T via MFMA; +cvec +h; LN; relu ----------
// One wave per 16-node block. Mt16 (64x256 f16, 32KB) staged in LDS with XOR swizzle.
// mfma_f32_16x16x32_f16 fragment maps (two stacked 16x16x16 blocks):
//   A: row = lane&15, k = 4*(lane>>4) + (e&3) + 16*(e>>2)
//   B: col = lane&15, same k map.  C/D: col = lane&15, row = 4*(lane>>4) + e  [m89-verified]
__global__ __launch_bounds__(256) void k_post_mfma(
    const f16* __restrict__ aggh16, const f16* __restrict__ Mt16,
    const float* __restrict__ cvec, const float* __restrict__ h,
    const float* __restrict__ gamma_, const float* __restrict__ beta_,
    float* __restrict__ out)
{
    __shared__ f16 Mlds[64 * 256];   // Mt[c][k] swizzled, 32 KB
    const int t = threadIdx.x;
    {   // stage: 16B chunk ch -> chunk ch ^ ((row c = ch>>5) & 7)
        const uint4* g = (const uint4*)Mt16;
        uint4* l = (uint4*)Mlds;
#pragma unroll
        for (int i = 0; i < 8; ++i) {
            int ch = i * 256 + t;
            l[ch ^ ((ch >> 5) & 7)] = g[ch];
        }
    }
    __syncthreads();
    const int lane = t & 63;
    const int l15 = lane & 15, lg = lane >> 4;
    float cv_r[4], ga_r[4], be_r[4];
#pragma unroll
    for (int ct = 0; ct < 4; ++ct) {
        int c = ct * 16 + l15;
        cv_r[ct] = cvec[c]; ga_r[ct] = gamma_[c]; be_r[ct] = beta_[c];
    }
    const int wid0 = (blockIdx.x * 256 + t) >> 6;
    const int nw = (gridDim.x * 256) >> 6;
    for (int blk = wid0; blk < N_NODES / 16; blk += nw) {
        f32x4 acc[4] = {{0.f,0.f,0.f,0.f},{0.f,0.f,0.f,0.f},{0.f,0.f,0.f,0.f},{0.f,0.f,0.f,0.f}};
        const f16* arow = aggh16 + (size_t)(blk * 16 + l15) * 256 + 4 * lg;
#pragma unroll
        for (int ks = 0; ks < 8; ++ks) {
            f16x4 alo = *(const f16x4*)(arow + ks * 32);
            f16x4 ahi = *(const f16x4*)(arow + ks * 32 + 16);
            f16x8 a;
            a[0]=alo[0]; a[1]=alo[1]; a[2]=alo[2]; a[3]=alo[3];
            a[4]=ahi[0]; a[5]=ahi[1]; a[6]=ahi[2]; a[7]=ahi[3];
#pragma unroll
            for (int ct = 0; ct < 4; ++ct) {
                const int c = ct * 16 + l15;
                const int sw = (c & 7) << 3;                    // f16-unit XOR swizzle
                const int u0 = (c * 256 + ks * 32 + 4 * lg);
                f16x4 blo = *(const f16x4*)(Mlds + (u0 ^ sw));
                f16x4 bhi = *(const f16x4*)(Mlds + ((u0 + 16) ^ sw));
                f16x8 b;
                b[0]=blo[0]; b[1]=blo[1]; b[2]=blo[2]; b[3]=blo[3];
                b[4]=bhi[0]; b[5]=bhi[1]; b[6]=bhi[2]; b[7]=bhi[3];
                acc[ct] = __builtin_amdgcn_mfma_f32_16x16x32_f16(a, b, acc[ct], 0, 0, 0);
            }
        }
        // epilogue: row r = blk*16 + 4*lg + e; cols ct*16 + l15; LN over 16-lane groups
#pragma unroll
        for (int e = 0; e < 4; ++e) {
            const int gr = blk * 16 + 4 * lg + e;
            float x[4];
            float s = 0.f;
#pragma unroll
            for (int ct = 0; ct < 4; ++ct) {
                x[ct] = acc[ct][e] + cv_r[ct] + h[(size_t)gr * 64 + ct * 16 + l15];
                s += x[ct];
            }
            s += __shfl_xor(s, 1); s += __shfl_xor(s, 2);
            s += __shfl_xor(s, 4); s += __shfl_xor(s, 8);
            const float mu = s * (1.0f / 64.0f);
            float v = 0.f;
#pragma unroll
            for (int ct = 0; ct < 4; ++ct) { float d = x[ct] - mu; v = fmaf(d, d, v); }
            v += __shfl_xor(v, 1); v += __shfl_xor(v, 2);
            v += __shfl_xor(v, 4); v += __shfl_xor(v, 8);
            const float rinv = rsqrtf(v * (1.0f / 64.0f) + LN_EPS);
#pragma unroll
            for (int ct = 0; ct < 4; ++ct) {
                float xn = (x[ct] - mu) * rinv;
                out[(size_t)gr * 64 + ct * 16 + l15] = fmaxf(xn * ga_r[ct] + be_r[ct], 0.0f);
            }
        }
    }
}

extern "C" void kernel_launch(void* const* d_in, const int* in_sizes, int n_in,
                              void* d_out, int out_size, void* d_ws, size_t ws_size,
                              hipStream_t stream) {
    const float* h      = (const float*)d_in[0];
    const int*   src    = (const int*)d_in[1];
    const int*   dst    = (const int*)d_in[2];
    const float* Wn     = (const float*)d_in[3];
    const float* bn     = (const float*)d_in[4];
    const float* att    = (const float*)d_in[5];
    const float* Ws     = (const float*)d_in[6];
    const float* bias   = (const float*)d_in[7];
    const float* gamma_ = (const float*)d_in[8];
    const float* beta_  = (const float*)d_in[9];
    float* out = (float*)d_out;

    char* ws = (char*)d_ws;
    size_t off = 0;
    auto alloc = [&](size_t bytes) { void* p = ws + off; off = (off + bytes + 255) & ~(size_t)255; return p; };
    __half* h16    = (__half*)alloc((size_t)N_NODES * 64 * 2);   // 6.4 MB
    f16*   aggh16  = (f16*)alloc((size_t)N_NODES * 256 * 2);     // 25.6 MB
    float* alpha_u = (float*)alloc((size_t)N_NODES * 4 * 4);
    float* alpha_v = (float*)alloc((size_t)N_NODES * 4 * 4);
    int*   deg     = (int*)alloc((size_t)N_NODES * 4);
    int*   rowptr  = (int*)alloc((size_t)(N_NODES + 1) * 4);
    int*   rank    = (int*)alloc((size_t)N_EDGES * 4);           // 3.2 MB
    int*   bsum    = (int*)alloc((size_t)NB_SCAN * 4);
    int*   boff    = (int*)alloc((size_t)NB_SCAN * 4);
    int*   csr_src = (int*)alloc((size_t)N_EDGES * 4);           // 3.2 MB
    float* qu      = (float*)alloc(256 * 4);
    float* qv      = (float*)alloc(256 * 4);
    float* cuv     = (float*)alloc(8 * 4);
    f16*   Mt16    = (f16*)alloc(16384 * 2);                     // 32 KB
    float* cvec    = (float*)alloc(64 * 4);

    hipMemsetAsync(deg, 0, (size_t)N_NODES * 4, stream);

    k_pre<<<66, 256, 0, stream>>>(Wn, bn, att, Ws, bias, qu, qv, cuv, Mt16, cvec);
    k_front2<<<ALPHA_BLOCKS + DEG_BLOCKS, 256, 0, stream>>>(h, dst, qu, qv, cuv,
                                                            h16, alpha_u, alpha_v, deg, rank);
    k_scan1<<<NB_SCAN, 256, 0, stream>>>(deg, rowptr, bsum);
    k_scan2<<<1, 256, 0, stream>>>(bsum, boff);
    k_scan3<<<NB_SCAN, 256, 0, stream>>>(rowptr, boff);
    k_scatter<<<DEG_BLOCKS, 256, 0, stream>>>(src, dst, rowptr, rank, csr_src);
    k_agg2<<<2048, 256, 0, stream>>>(rowptr, csr_src, alpha_u, alpha_v, h16, aggh16, 0, N_NODES / 2);
    k_agg2<<<2048, 256, 0, stream>>>(rowptr, csr_src, alpha_u, alpha_v, h16, aggh16, N_NODES / 2, N_NODES);
    k_post_mfma<<<782, 256, 0, stream>>>(aggh16, Mt16, cvec, h, gamma_, beta_, out);
}

// Round 11
// 255.751 us; speedup vs baseline: 1.3221x; 1.0946x over previous
//
#include <hip/hip_runtime.h>
#include <hip/hip_fp16.h>

#define N_NODES 50000
#define N_EDGES 800000
#define NEG_SLOPE 0.2f
#define LN_EPS 1e-5f
#define NB_SCAN 196      // ceil(N_NODES/256)
#define ALPHA_BLOCKS 1024
#define DEG_BLOCKS 3125  // ceil(N_EDGES/256)

typedef _Float16 f16;
typedef f16 f16x4 __attribute__((ext_vector_type(4)));
typedef f16 f16x8 __attribute__((ext_vector_type(8)));
typedef float f32x4 __attribute__((ext_vector_type(4)));

// ---------------- k_pre: tiny precomputes ----------------
// Mt16[c][hd*64+k] = (f16) sum_j Wn[k][hd*64+j] * Ws[hd*64+j][c]   (transposed, fp16)
// qu[hd][k], qv[hd][k]: alpha projection vectors; cuv: bias dots; cvec = bias + bn@Ws
__global__ __launch_bounds__(256) void k_pre(
    const float* __restrict__ Wn, const float* __restrict__ bn,
    const float* __restrict__ att, const float* __restrict__ Ws,
    const float* __restrict__ bias,
    float* __restrict__ qu, float* __restrict__ qv, float* __restrict__ cuv,
    f16* __restrict__ Mt16, float* __restrict__ cvec)
{
    const int b = blockIdx.x, t = threadIdx.x;
    if (b < 64) {
        int e = b * 256 + t;                 // [0, 16384)
        int hd = e >> 12, k = (e >> 6) & 63, c = e & 63;
        float s = 0.f;
        for (int j = 0; j < 64; ++j)
            s = fmaf(Wn[k * 256 + hd * 64 + j], Ws[(hd * 64 + j) * 64 + c], s);
        Mt16[c * 256 + hd * 64 + k] = (f16)s;
    } else if (b == 64) {
        int hd = t >> 6, k = t & 63;
        float su = 0.f, sv = 0.f;
        for (int j = 0; j < 64; ++j) {
            float w = Wn[k * 256 + hd * 64 + j];
            su = fmaf(w, att[hd * 128 + j], su);
            sv = fmaf(w, att[hd * 128 + 64 + j], sv);
        }
        qu[hd * 64 + k] = su;
        qv[hd * 64 + k] = sv;
        if (t < 8) {
            int hh = t & 3;
            const float* a = att + hh * 128 + (t >> 2) * 64;
            float s = 0.f;
            for (int j = 0; j < 64; ++j) s = fmaf(bn[hh * 64 + j], a[j], s);
            cuv[t] = s;                      // [0..3]=cu, [4..7]=cv
        }
    } else {
        if (t < 64) {
            float s = bias[t];
            for (int kk = 0; kk < 256; ++kk) s = fmaf(bn[kk], Ws[kk * 64 + t], s);
            cvec[t] = s;
        }
    }
}

// ---------------- k_front2: [0,ALPHA_BLOCKS) alphas + h16 cast; rest: degree+rank ----------------
__global__ __launch_bounds__(256) void k_front2(
    const float* __restrict__ h, const int* __restrict__ dst,
    const float* __restrict__ qu, const float* __restrict__ qv, const float* __restrict__ cuv,
    __half* __restrict__ h16, float* __restrict__ alpha_u, float* __restrict__ alpha_v,
    int* __restrict__ deg, int* __restrict__ rank)
{
    const int t = threadIdx.x;
    if (blockIdx.x >= ALPHA_BLOCKS) {
        int e = (blockIdx.x - ALPHA_BLOCKS) * 256 + t;
        if (e < N_EDGES) rank[e] = atomicAdd(&deg[dst[e]], 1);
        return;
    }
    const int lane = t & 63;
    const int wid = blockIdx.x * 4 + (t >> 6);
    const float qur0 = qu[lane], qur1 = qu[64 + lane], qur2 = qu[128 + lane], qur3 = qu[192 + lane];
    const float qvr0 = qv[lane], qvr1 = qv[64 + lane], qvr2 = qv[128 + lane], qvr3 = qv[192 + lane];
    const float4 cu = *(const float4*)cuv;
    const float4 cv = *(const float4*)(cuv + 4);
    for (int n = wid; n < N_NODES; n += ALPHA_BLOCKS * 4) {
        float hv = h[(size_t)n * 64 + lane];
        h16[(size_t)n * 64 + lane] = __float2half(hv);
        float pu0 = hv * qur0, pu1 = hv * qur1, pu2 = hv * qur2, pu3 = hv * qur3;
        float pv0 = hv * qvr0, pv1 = hv * qvr1, pv2 = hv * qvr2, pv3 = hv * qvr3;
#pragma unroll
        for (int off = 32; off; off >>= 1) {
            pu0 += __shfl_xor(pu0, off);
            pu1 += __shfl_xor(pu1, off);
            pu2 += __shfl_xor(pu2, off);
            pu3 += __shfl_xor(pu3, off);
            pv0 += __shfl_xor(pv0, off);
            pv1 += __shfl_xor(pv1, off);
            pv2 += __shfl_xor(pv2, off);
            pv3 += __shfl_xor(pv3, off);
        }
        if (lane == 0) {
            *(float4*)(alpha_u + n * 4) = make_float4(pu0 + cu.x, pu1 + cu.y, pu2 + cu.z, pu3 + cu.w);
            *(float4*)(alpha_v + n * 4) = make_float4(pv0 + cv.x, pv1 + cv.y, pv2 + cv.z, pv3 + cv.w);
        }
    }
}

// ---------------- scan (3 small stages) ----------------
__device__ __forceinline__ int wave_incl_scan(int x, int lane) {
#pragma unroll
    for (int off = 1; off < 64; off <<= 1) {
        int y = __shfl_up(x, off);
        if (lane >= off) x += y;
    }
    return x;
}

__global__ __launch_bounds__(256) void k_scan1(const int* __restrict__ deg,
                                               int* __restrict__ rowptr, int* __restrict__ bsum) {
    __shared__ int wsum[4];
    const int t = threadIdx.x, lane = t & 63, w = t >> 6;
    const int i = blockIdx.x * 256 + t;
    int x = (i < N_NODES) ? deg[i] : 0;
    int incl = wave_incl_scan(x, lane);
    if (lane == 63) wsum[w] = incl;
    __syncthreads();
    int pre = 0;
    for (int ww = 0; ww < w; ++ww) pre += wsum[ww];
    if (i < N_NODES) rowptr[i] = pre + incl - x;
    if (t == 255) bsum[blockIdx.x] = pre + incl;
}

__global__ __launch_bounds__(256) void k_scan2(const int* __restrict__ bsum, int* __restrict__ boff) {
    __shared__ int wsum[4];
    const int t = threadIdx.x, lane = t & 63, w = t >> 6;
    int x = (t < NB_SCAN) ? bsum[t] : 0;
    int incl = wave_incl_scan(x, lane);
    if (lane == 63) wsum[w] = incl;
    __syncthreads();
    int pre = 0;
    for (int ww = 0; ww < w; ++ww) pre += wsum[ww];
    if (t < NB_SCAN) boff[t] = pre + incl - x;
}

__global__ __launch_bounds__(256) void k_scan3(int* __restrict__ rowptr, const int* __restrict__ boff) {
    const int i = blockIdx.x * 256 + threadIdx.x;
    if (i < N_NODES) rowptr[i] += boff[blockIdx.x];
    if (i == 0) rowptr[N_NODES] = N_EDGES;
}

// ---------------- scatter: atomic-free; also precompute per-edge softmax weights ----------------
// w[e,h] = exp(leaky(alpha_u[src]+alpha_v[dst])) computed ONCE per edge (not per lane later).
__global__ __launch_bounds__(256) void k_scatter(
    const int* __restrict__ src, const int* __restrict__ dst,
    const int* __restrict__ rowptr, const int* __restrict__ rank,
    const float* __restrict__ alpha_u, const float* __restrict__ alpha_v,
    int* __restrict__ csr_src, float* __restrict__ csr_w)
{
    int e = blockIdx.x * 256 + threadIdx.x;
    if (e >= N_EDGES) return;
    const int s = src[e], d = dst[e];
    const int pos = rowptr[d] + rank[e];
    csr_src[pos] = s;
    const float4 au = *(const float4*)(alpha_u + (size_t)s * 4);
    const float4 av = *(const float4*)(alpha_v + (size_t)d * 4);
    float l0 = au.x + av.x; l0 = l0 > 0.f ? l0 : NEG_SLOPE * l0;
    float l1 = au.y + av.y; l1 = l1 > 0.f ? l1 : NEG_SLOPE * l1;
    float l2 = au.z + av.z; l2 = l2 > 0.f ? l2 : NEG_SLOPE * l2;
    float l3 = au.w + av.w; l3 = l3 > 0.f ? l3 : NEG_SLOPE * l3;
    *(float4*)(csr_w + (size_t)pos * 4) =
        make_float4(__expf(l0), __expf(l1), __expf(l2), __expf(l3));
}

// ---------------- k_agg3: one wave per node; precomputed weights; gather h16[src] ----------------
// per edge per lane: 1 h16 load (2B), 1 broadcast float4 w load, 4 cndmask+4 add+4 fma.
__global__ __launch_bounds__(256) void k_agg3(
    const int* __restrict__ rowptr, const int* __restrict__ csr_src,
    const float* __restrict__ csr_w, const __half* __restrict__ h16,
    f16* __restrict__ aggh16, int n0, int n1)
{
    const int lane = threadIdx.x & 63;
    const int wid = (blockIdx.x * 256 + threadIdx.x) >> 6;
    const int nwaves = (gridDim.x * 256) >> 6;
    for (int n = n0 + wid; n < n1; n += nwaves) {
        const int r0 = rowptr[n], r1 = rowptr[n + 1];
        float d0 = 0.f, d1 = 0.f, d2 = 0.f, d3 = 0.f;
        float a0 = 0.f, a1 = 0.f, a2 = 0.f, a3 = 0.f;
        const int rlast = r1 - 1;
        for (int j = r0; j < r1; j += 8) {
            int jdx[8], s[8];
#pragma unroll
            for (int i = 0; i < 8; ++i) {
                int jj = j + i;
                jdx[i] = jj < rlast ? jj : rlast;
                s[i] = __builtin_amdgcn_readfirstlane(csr_src[jdx[i]]);
            }
            float hv[8];
#pragma unroll
            for (int i = 0; i < 8; ++i)
                hv[i] = __half2float(h16[(size_t)s[i] * 64 + lane]);
            float4 w[8];
#pragma unroll
            for (int i = 0; i < 8; ++i)
                w[i] = *(const float4*)(csr_w + (size_t)jdx[i] * 4);
#pragma unroll
            for (int i = 0; i < 8; ++i) {
                const bool valid = (j + i < r1);
                float e0 = valid ? w[i].x : 0.f;
                float e1 = valid ? w[i].y : 0.f;
                float e2 = valid ? w[i].z : 0.f;
                float e3 = valid ? w[i].w : 0.f;
                d0 += e0; a0 = fmaf(e0, hv[i], a0);
                d1 += e1; a1 = fmaf(e1, hv[i], a1);
                d2 += e2; a2 = fmaf(e2, hv[i], a2);
                d3 += e3; a3 = fmaf(e3, hv[i], a3);
            }
        }
        const float i0 = 1.0f / fmaxf(d0, 1e-16f);
        const float i1 = 1.0f / fmaxf(d1, 1e-16f);
        const float i2 = 1.0f / fmaxf(d2, 1e-16f);
        const float i3 = 1.0f / fmaxf(d3, 1e-16f);
        f16* __restrict__ arow = aggh16 + (size_t)n * 256;
        arow[lane]       = (f16)(a0 * i0);
        arow[64 + lane]  = (f16)(a1 * i1);
        arow[128 + lane] = (f16)(a2 * i2);
        arow[192 + lane] = (f16)(a3 * i3);
    }
}

// ---------------- k_post_mfma: h_new = aggh16 @ Mt16^T via MFMA; +cvec +h; LN; relu ----------
// One wave per 16-node block. Mt16 (64x256 f16, 32KB) staged in LDS with XOR swizzle.
// mfma_f32_16x16x32_f16 fragment maps (two stacked 16x16x16 blocks):
//   A: row = lane&15, k = 4*(lane>>4) + (e&3) + 16*(e>>2)
//   B: col = lane&15, same k map.  C/D: col = lane&15, row = 4*(lane>>4) + e  [m89-verified]
__global__ __launch_bounds__(256) void k_post_mfma(
    const f16* __restrict__ aggh16, const f16* __restrict__ Mt16,
    const float* __restrict__ cvec, const float* __restrict__ h,
    const float* __restrict__ gamma_, const float* __restrict__ beta_,
    float* __restrict__ out)
{
    __shared__ f16 Mlds[64 * 256];   // Mt[c][k] swizzled, 32 KB
    const int t = threadIdx.x;
    {   // stage: 16B chunk ch -> chunk ch ^ ((row c = ch>>5) & 7)
        const uint4* g = (const uint4*)Mt16;
        uint4* l = (uint4*)Mlds;
#pragma unroll
        for (int i = 0; i < 8; ++i) {
            int ch = i * 256 + t;
            l[ch ^ ((ch >> 5) & 7)] = g[ch];
        }
    }
    __syncthreads();
    const int lane = t & 63;
    const int l15 = lane & 15, lg = lane >> 4;
    float cv_r[4], ga_r[4], be_r[4];
#pragma unroll
    for (int ct = 0; ct < 4; ++ct) {
        int c = ct * 16 + l15;
        cv_r[ct] = cvec[c]; ga_r[ct] = gamma_[c]; be_r[ct] = beta_[c];
    }
    const int wid0 = (blockIdx.x * 256 + t) >> 6;
    const int nw = (gridDim.x * 256) >> 6;
    for (int blk = wid0; blk < N_NODES / 16; blk += nw) {
        f32x4 acc[4] = {{0.f,0.f,0.f,0.f},{0.f,0.f,0.f,0.f},{0.f,0.f,0.f,0.f},{0.f,0.f,0.f,0.f}};
        const f16* arow = aggh16 + (size_t)(blk * 16 + l15) * 256 + 4 * lg;
#pragma unroll
        for (int ks = 0; ks < 8; ++ks) {
            f16x4 alo = *(const f16x4*)(arow + ks * 32);
            f16x4 ahi = *(const f16x4*)(arow + ks * 32 + 16);
            f16x8 a;
            a[0]=alo[0]; a[1]=alo[1]; a[2]=alo[2]; a[3]=alo[3];
            a[4]=ahi[0]; a[5]=ahi[1]; a[6]=ahi[2]; a[7]=ahi[3];
#pragma unroll
            for (int ct = 0; ct < 4; ++ct) {
                const int c = ct * 16 + l15;
                const int sw = (c & 7) << 3;                    // f16-unit XOR swizzle
                const int u0 = (c * 256 + ks * 32 + 4 * lg);
                f16x4 blo = *(const f16x4*)(Mlds + (u0 ^ sw));
                f16x4 bhi = *(const f16x4*)(Mlds + ((u0 + 16) ^ sw));
                f16x8 b;
                b[0]=blo[0]; b[1]=blo[1]; b[2]=blo[2]; b[3]=blo[3];
                b[4]=bhi[0]; b[5]=bhi[1]; b[6]=bhi[2]; b[7]=bhi[3];
                acc[ct] = __builtin_amdgcn_mfma_f32_16x16x32_f16(a, b, acc[ct], 0, 0, 0);
            }
        }
        // epilogue: row r = blk*16 + 4*lg + e; cols ct*16 + l15; LN over 16-lane groups
#pragma unroll
        for (int e = 0; e < 4; ++e) {
            const int gr = blk * 16 + 4 * lg + e;
            float x[4];
            float s = 0.f;
#pragma unroll
            for (int ct = 0; ct < 4; ++ct) {
                x[ct] = acc[ct][e] + cv_r[ct] + h[(size_t)gr * 64 + ct * 16 + l15];
                s += x[ct];
            }
            s += __shfl_xor(s, 1); s += __shfl_xor(s, 2);
            s += __shfl_xor(s, 4); s += __shfl_xor(s, 8);
            const float mu = s * (1.0f / 64.0f);
            float v = 0.f;
#pragma unroll
            for (int ct = 0; ct < 4; ++ct) { float d = x[ct] - mu; v = fmaf(d, d, v); }
            v += __shfl_xor(v, 1); v += __shfl_xor(v, 2);
            v += __shfl_xor(v, 4); v += __shfl_xor(v, 8);
            const float rinv = rsqrtf(v * (1.0f / 64.0f) + LN_EPS);
#pragma unroll
            for (int ct = 0; ct < 4; ++ct) {
                float xn = (x[ct] - mu) * rinv;
                out[(size_t)gr * 64 + ct * 16 + l15] = fmaxf(xn * ga_r[ct] + be_r[ct], 0.0f);
            }
        }
    }
}

extern "C" void kernel_launch(void* const* d_in, const int* in_sizes, int n_in,
                              void* d_out, int out_size, void* d_ws, size_t ws_size,
                              hipStream_t stream) {
    const float* h      = (const float*)d_in[0];
    const int*   src    = (const int*)d_in[1];
    const int*   dst    = (const int*)d_in[2];
    const float* Wn     = (const float*)d_in[3];
    const float* bn     = (const float*)d_in[4];
    const float* att    = (const float*)d_in[5];
    const float* Ws     = (const float*)d_in[6];
    const float* bias   = (const float*)d_in[7];
    const float* gamma_ = (const float*)d_in[8];
    const float* beta_  = (const float*)d_in[9];
    float* out = (float*)d_out;

    char* ws = (char*)d_ws;
    size_t off = 0;
    auto alloc = [&](size_t bytes) { void* p = ws + off; off = (off + bytes + 255) & ~(size_t)255; return p; };
    __half* h16    = (__half*)alloc((size_t)N_NODES * 64 * 2);   // 6.4 MB
    f16*   aggh16  = (f16*)alloc((size_t)N_NODES * 256 * 2);     // 25.6 MB
    float* alpha_u = (float*)alloc((size_t)N_NODES * 4 * 4);
    float* alpha_v = (float*)alloc((size_t)N_NODES * 4 * 4);
    int*   deg     = (int*)alloc((size_t)N_NODES * 4);
    int*   rowptr  = (int*)alloc((size_t)(N_NODES + 1) * 4);
    int*   rank    = (int*)alloc((size_t)N_EDGES * 4);           // 3.2 MB
    int*   bsum    = (int*)alloc((size_t)NB_SCAN * 4);
    int*   boff    = (int*)alloc((size_t)NB_SCAN * 4);
    int*   csr_src = (int*)alloc((size_t)N_EDGES * 4);           // 3.2 MB
    float* csr_w   = (float*)alloc((size_t)N_EDGES * 4 * 4);     // 12.8 MB
    float* qu      = (float*)alloc(256 * 4);
    float* qv      = (float*)alloc(256 * 4);
    float* cuv     = (float*)alloc(8 * 4);
    f16*   Mt16    = (f16*)alloc(16384 * 2);                     // 32 KB
    float* cvec    = (float*)alloc(64 * 4);

    hipMemsetAsync(deg, 0, (size_t)N_NODES * 4, stream);

    k_pre<<<66, 256, 0, stream>>>(Wn, bn, att, Ws, bias, qu, qv, cuv, Mt16, cvec);
    k_front2<<<ALPHA_BLOCKS + DEG_BLOCKS, 256, 0, stream>>>(h, dst, qu, qv, cuv,
                                                            h16, alpha_u, alpha_v, deg, rank);
    k_scan1<<<NB_SCAN, 256, 0, stream>>>(deg, rowptr, bsum);
    k_scan2<<<1, 256, 0, stream>>>(bsum, boff);
    k_scan3<<<NB_SCAN, 256, 0, stream>>>(rowptr, boff);
    k_scatter<<<DEG_BLOCKS, 256, 0, stream>>>(src, dst, rowptr, rank, alpha_u, alpha_v,
                                              csr_src, csr_w);
    k_agg3<<<2048, 256, 0, stream>>>(rowptr, csr_src, csr_w, h16, aggh16, 0, N_NODES / 2);
    k_agg3<<<2048, 256, 0, stream>>>(rowptr, csr_src, csr_w, h16, aggh16, N_NODES / 2, N_NODES);
    k_post_mfma<<<782, 256, 0, stream>>>(aggh16, Mt16, cvec, h, gamma_, beta_, out);
}